// Round 9
// baseline (114.654 us; speedup 1.0000x reference)
//
#include <hip/hip_runtime.h>

#define N_POINTS 500000
#define K_CENT   512
#define W_DIM    64
#define N_TILES  (N_POINTS / 32)          // 15625 exact
#define N_JOBS3  ((N_TILES + 2) / 3)      // 5209 (last job: 1 valid tile)

typedef _Float16 half8 __attribute__((ext_vector_type(8)));
typedef float    f32x16 __attribute__((ext_vector_type(16)));

// ---- pre-kernel 1: codebook -> fragment-ordered f16 hi/lo planes of w = -2*c.
// Layout: [t:16][plane:2][s:4][lane:64][j:8] -> 8 KB/chunk, 128 KB total.
// A-fragment mapping (mfma_f32_32x32x16_f16, verified R2): lane l holds
// row=l&31, k=(l>>5)*8+j of K-step s => centroid c = t*32+(l&31),
// dim d = s*16 + (l>>5)*8 + j. lo plane = unscaled residual (verified R8).
__global__ void cvt_kernel(const float* __restrict__ cb,
                           _Float16* __restrict__ cbf) {
    int id = blockIdx.x * 256 + threadIdx.x;           // 4096 ids
    if (id >= K_CENT * 8) return;
    int c = id >> 3, o = (id & 7) * 8;                 // centroid, dim base
    int t = c >> 5, r = c & 31;
    int s = o >> 4, half = (o >> 3) & 1;
    int lane = half * 32 + r;
    const float* src = cb + (size_t)c * W_DIM + o;
    half8 h, l;
#pragma unroll
    for (int j = 0; j < 8; ++j) {
        float w = -2.0f * src[j];
        _Float16 hh = (_Float16)w;                     // RNE
        h[j] = hh;
        l[j] = (_Float16)(w - (float)hh);              // unscaled residual
    }
    size_t base_h = ((size_t)(t * 2 + 0) * 4 + s) * 512 + (size_t)lane * 8;
    size_t base_l = ((size_t)(t * 2 + 1) * 4 + s) * 512 + (size_t)lane * 8;
    *(half8*)(cbf + base_h) = h;
    *(half8*)(cbf + base_l) = l;
}

// ---- pre-kernel 2: c2[c] = ||c||^2 in double (deterministic)
__global__ void c2_kernel(const float* __restrict__ cb, float* __restrict__ c2) {
    int c = blockIdx.x * 256 + threadIdx.x;
    if (c >= K_CENT) return;
    const float4* row = (const float4*)(cb + (size_t)c * W_DIM);
    double s = 0.0;
#pragma unroll
    for (int j = 0; j < W_DIM / 4; ++j) {
        float4 v = row[j];
        s += (double)v.x * v.x + (double)v.y * v.y + (double)v.z * v.z + (double)v.w * v.w;
    }
    c2[c] = (float)s;
}

// 36 MFMAs for chunk T: 3 tiles x 3 planes x 4 K-steps, one acc chain per
// tile, C-in = permuted c2 vector QC. A single-buffered (ah/al reused).
#define MFMA3_CHUNK(QC, A0, A1, A2)                                                \
    {                                                                              \
        A0 = __builtin_amdgcn_mfma_f32_32x32x16_f16(ah[0], b0h[0], QC, 0, 0, 0);   \
        A1 = __builtin_amdgcn_mfma_f32_32x32x16_f16(ah[0], b1h[0], QC, 0, 0, 0);   \
        A2 = __builtin_amdgcn_mfma_f32_32x32x16_f16(ah[0], b2h[0], QC, 0, 0, 0);   \
        A0 = __builtin_amdgcn_mfma_f32_32x32x16_f16(al[0], b0h[0], A0, 0, 0, 0);   \
        A1 = __builtin_amdgcn_mfma_f32_32x32x16_f16(al[0], b1h[0], A1, 0, 0, 0);   \
        A2 = __builtin_amdgcn_mfma_f32_32x32x16_f16(al[0], b2h[0], A2, 0, 0, 0);   \
        A0 = __builtin_amdgcn_mfma_f32_32x32x16_f16(ah[0], b0l[0], A0, 0, 0, 0);   \
        A1 = __builtin_amdgcn_mfma_f32_32x32x16_f16(ah[0], b1l[0], A1, 0, 0, 0);   \
        A2 = __builtin_amdgcn_mfma_f32_32x32x16_f16(ah[0], b2l[0], A2, 0, 0, 0);   \
        _Pragma("unroll")                                                          \
        for (int s = 1; s < 4; ++s) {                                              \
            A0 = __builtin_amdgcn_mfma_f32_32x32x16_f16(ah[s], b0h[s], A0, 0, 0, 0); \
            A1 = __builtin_amdgcn_mfma_f32_32x32x16_f16(ah[s], b1h[s], A1, 0, 0, 0); \
            A2 = __builtin_amdgcn_mfma_f32_32x32x16_f16(ah[s], b2h[s], A2, 0, 0, 0); \
            A0 = __builtin_amdgcn_mfma_f32_32x32x16_f16(al[s], b0h[s], A0, 0, 0, 0); \
            A1 = __builtin_amdgcn_mfma_f32_32x32x16_f16(al[s], b1h[s], A1, 0, 0, 0); \
            A2 = __builtin_amdgcn_mfma_f32_32x32x16_f16(al[s], b2h[s], A2, 0, 0, 0); \
            A0 = __builtin_amdgcn_mfma_f32_32x32x16_f16(ah[s], b0l[s], A0, 0, 0, 0); \
            A1 = __builtin_amdgcn_mfma_f32_32x32x16_f16(ah[s], b1l[s], A1, 0, 0, 0); \
            A2 = __builtin_amdgcn_mfma_f32_32x32x16_f16(ah[s], b2l[s], A2, 0, 0, 0); \
        }                                                                          \
    }

// Prefetch chunk T's A-fragments (into the single ah/al set - regs are dead
// after the preceding MFMA block) and its permuted c2 vector. Issued BEFORE
// argmin so the ~250cy L2 latency hides under the argmin VALU.
#define PREFETCH(T, QN)                                                            \
    {                                                                              \
        int t_ = (T);                                                              \
        if (t_ < 16) {                                                             \
            const _Float16* nb = cbf + (size_t)t_ * 4096 + (size_t)lane * 8;       \
            ah[0] = *(const half8*)(nb + 0 * 512);                                 \
            ah[1] = *(const half8*)(nb + 1 * 512);                                 \
            ah[2] = *(const half8*)(nb + 2 * 512);                                 \
            ah[3] = *(const half8*)(nb + 3 * 512);                                 \
            al[0] = *(const half8*)(nb + 2048 + 0 * 512);                          \
            al[1] = *(const half8*)(nb + 2048 + 1 * 512);                          \
            al[2] = *(const half8*)(nb + 2048 + 2 * 512);                          \
            al[3] = *(const half8*)(nb + 2048 + 3 * 512);                          \
            QN = *(const f32x16*)&c2s[t_ * 32 + half16];                           \
        }                                                                          \
    }

// Binary-descent argmin over 16 values (already include c2 via C-in).
// Each level prefers LEFT on tie -> smallest ji -> first-index-wins (ci is
// monotone in ji for fixed half). fmin returns an input bit-exactly.
#define ARGMIN_TILE(AM, BD, BI, T_)                                            \
    {                                                                          \
        float a0 = fminf(AM[0], AM[1]),   a1 = fminf(AM[2], AM[3]);            \
        float a2 = fminf(AM[4], AM[5]),   a3 = fminf(AM[6], AM[7]);            \
        float a4 = fminf(AM[8], AM[9]),   a5 = fminf(AM[10], AM[11]);          \
        float a6 = fminf(AM[12], AM[13]), a7 = fminf(AM[14], AM[15]);          \
        float b0 = fminf(a0, a1), b1 = fminf(a2, a3);                          \
        float b2 = fminf(a4, a5), b3 = fminf(a6, a7);                          \
        float c0 = fminf(b0, b1), c1 = fminf(b2, b3);                          \
        float m  = fminf(c0, c1);                                              \
        bool  L3 = (m == c0);                                                  \
        float bL = L3 ? b0 : b2;                                               \
        bool  L2 = (m == bL);                                                  \
        float aL = L3 ? (L2 ? a0 : a2) : (L2 ? a4 : a6);                       \
        bool  L1 = (m == aL);                                                  \
        float vE = L3 ? (L2 ? (L1 ? AM[0] : AM[2]) : (L1 ? AM[4] : AM[6]))     \
                      : (L2 ? (L1 ? AM[8] : AM[10]) : (L1 ? AM[12] : AM[14])); \
        bool  L0 = (m == vE);                                                  \
        int ji = (L3 ? 0 : 8) | (L2 ? 0 : 4) | (L1 ? 0 : 2) | (L0 ? 0 : 1);    \
        int ci = (T_) * 32 + half4 + ((ji >> 2) << 3) + (ji & 3);              \
        bool imp = m < BD;                                                     \
        BD = imp ? m : BD;                                                     \
        BI = imp ? ci : BI;                                                    \
    }

#define ARGMIN3(T, A0, A1, A2)                                                 \
    {                                                                          \
        ARGMIN_TILE(A0, bd0, bi0, T)                                           \
        ARGMIN_TILE(A1, bd1, bi1, T)                                           \
        ARGMIN_TILE(A2, bd2, bi2, T)                                           \
    }

// B-tile load+convert: f16 hi + unscaled lo residual, plus ||x||^2 partial.
#define LOADB(BH, BL, P, X2)                                                   \
    {                                                                          \
        _Pragma("unroll")                                                      \
        for (int s = 0; s < 4; ++s) {                                          \
            const float4* xp = (const float4*)(X + (size_t)(P) * W_DIM + s * 16 + kb); \
            float4 f0 = xp[0], f1 = xp[1];                                     \
            float fa[8] = {f0.x, f0.y, f0.z, f0.w, f1.x, f1.y, f1.z, f1.w};    \
            _Pragma("unroll")                                                  \
            for (int j = 0; j < 8; ++j) {                                      \
                _Float16 hh = (_Float16)fa[j];                                 \
                BH[s][j] = hh;                                                 \
                BL[s][j] = (_Float16)(fa[j] - (float)hh);                      \
                X2 = fmaf(fa[j], fa[j], X2);                                   \
            }                                                                  \
        }                                                                      \
    }

// ---- main kernel: 4 waves/block, each wave THREE 32-point tiles (96 pts).
// Per chunk: 36 MFMAs in 3 independent 12-chains (issue 1152cy covers dep
// latency); A single-buffered, prefetch+q issued post-MFMA / pre-argmin.
__global__ __launch_bounds__(256, 2)
void kmeans_mfma(const float* __restrict__ X,
                 const _Float16* __restrict__ cbf,
                 const float* __restrict__ c2,
                 float* __restrict__ out_idx,
                 float* __restrict__ out_dist) {
    // c2 permuted so each lane's 16 C-in values are contiguous:
    // c2s[t*32 + h*16 + j] = c2[t*32 + h*4 + (j>>2)*8 + (j&3)]
    __shared__ __align__(64) float c2s[K_CENT];
    int tid = threadIdx.x;
    {
        int i = tid;
        int t = i >> 5, h = (i >> 4) & 1, j = i & 15;
        c2s[i] = c2[t * 32 + h * 4 + ((j >> 2) << 3) + (j & 3)];
        i = tid + 256;
        t = i >> 5; h = (i >> 4) & 1; j = i & 15;
        c2s[i] = c2[t * 32 + h * 4 + ((j >> 2) << 3) + (j & 3)];
    }
    __syncthreads();

    int wave = tid >> 6;
    int lane = tid & 63;
    int half = lane >> 5;           // 0/1
    int l31  = lane & 31;
    int kb   = half * 8;
    int half4  = half * 4;
    int half16 = half * 16;

    int job = blockIdx.x * 4 + wave;
    if (job >= N_JOBS3) return;

    int t0 = job * 3;
    int  p0 = t0 * 32 + l31;
    bool ok1 = (t0 + 1) < N_TILES;
    bool ok2 = (t0 + 2) < N_TILES;
    int  p1 = ok1 ? (p0 + 32) : p0;
    int  p2 = ok2 ? (p0 + 64) : p0;

    // ---- B operands for 3 tiles
    half8 b0h[4], b0l[4], b1h[4], b1l[4], b2h[4], b2l[4];
    float x20 = 0.f, x21 = 0.f, x22 = 0.f;
    LOADB(b0h, b0l, p0, x20)
    LOADB(b1h, b1l, p1, x21)
    LOADB(b2h, b2l, p2, x22)
    x20 += __shfl_xor(x20, 32);     // halves hold disjoint dims of same point
    x21 += __shfl_xor(x21, 32);
    x22 += __shfl_xor(x22, 32);

    float bd0 = 3.4e38f, bd1 = 3.4e38f, bd2 = 3.4e38f;
    int   bi0 = 0,       bi1 = 0,       bi2 = 0;

    // A fragments: SINGLE buffer (reused every chunk); q C-in alternates P/Q.
    half8 ah[4], al[4];
    f32x16 qP, qQ, accP0, accP1, accP2, accQ0, accQ1, accQ2;
    PREFETCH(0, qP)

#pragma unroll 1
    for (int tt = 0; tt < 8; ++tt) {
        MFMA3_CHUNK(qP, accP0, accP1, accP2)
        PREFETCH(2 * tt + 1, qQ)
        ARGMIN3(2 * tt, accP0, accP1, accP2)
        MFMA3_CHUNK(qQ, accQ0, accQ1, accQ2)
        PREFETCH(2 * tt + 2, qP)
        ARGMIN3(2 * tt + 1, accQ0, accQ1, accQ2)
    }

    // combine the two lane-halves (disjoint centroid rows of the same point)
    {
        float od = __shfl_xor(bd0, 32); int oi = __shfl_xor(bi0, 32);
        if (od < bd0 || (od == bd0 && oi < bi0)) { bd0 = od; bi0 = oi; }
        od = __shfl_xor(bd1, 32); oi = __shfl_xor(bi1, 32);
        if (od < bd1 || (od == bd1 && oi < bi1)) { bd1 = od; bi1 = oi; }
        od = __shfl_xor(bd2, 32); oi = __shfl_xor(bi2, 32);
        if (od < bd2 || (od == bd2 && oi < bi2)) { bd2 = od; bi2 = oi; }
    }

    if (half == 0) {
        out_idx[p0]  = (float)bi0;
        out_dist[p0] = sqrtf(fmaxf(bd0 + x20, 0.f));
        if (ok1) {
            out_idx[p1]  = (float)bi1;
            out_dist[p1] = sqrtf(fmaxf(bd1 + x21, 0.f));
        }
        if (ok2) {
            out_idx[p2]  = (float)bi2;
            out_dist[p2] = sqrtf(fmaxf(bd2 + x22, 0.f));
        }
    }
}

extern "C" void kernel_launch(void* const* d_in, const int* in_sizes, int n_in,
                              void* d_out, int out_size, void* d_ws, size_t ws_size,
                              hipStream_t stream) {
    const float* X  = (const float*)d_in[0];
    const float* cb = (const float*)d_in[1];
    float* out      = (float*)d_out;

    // workspace: fragment-ordered codebook 128KB | c2 2KB
    _Float16* cbf = (_Float16*)d_ws;
    float*    c2  = (float*)(cbf + (size_t)K_CENT * W_DIM * 2);

    hipLaunchKernelGGL(cvt_kernel, dim3((K_CENT * 8 + 255) / 256), dim3(256), 0, stream, cb, cbf);
    hipLaunchKernelGGL(c2_kernel, dim3((K_CENT + 255) / 256), dim3(256), 0, stream, cb, c2);

    hipLaunchKernelGGL(kmeans_mfma, dim3((N_JOBS3 + 3) / 4), dim3(256), 0, stream,
                       X, cbf, c2, out, out + N_POINTS);
}

// Round 10
// 112.462 us; speedup vs baseline: 1.0195x; 1.0195x over previous
//
#include <hip/hip_runtime.h>

#define N_POINTS 500000
#define K_CENT   512
#define W_DIM    64
#define N_JOBS   ((N_POINTS + 63) / 64)   // 7813 (last job: tile1 invalid)

typedef _Float16 half8 __attribute__((ext_vector_type(8)));
typedef float    f32x16 __attribute__((ext_vector_type(16)));

// ---- pre-kernel 1: codebook -> fragment-ordered f16 hi/lo planes of w = -2*c.
// Layout: [t:16][plane:2][s:4][lane:64][j:8] -> 8 KB/chunk, 128 KB total.
// A-fragment mapping (mfma_f32_32x32x16_f16, verified R2): lane l holds
// row=l&31, k=(l>>5)*8+j of K-step s => centroid c = t*32+(l&31),
// dim d = s*16 + (l>>5)*8 + j. lo plane = unscaled residual (verified R8).
__global__ void cvt_kernel(const float* __restrict__ cb,
                           _Float16* __restrict__ cbf) {
    int id = blockIdx.x * 256 + threadIdx.x;           // 4096 ids
    if (id >= K_CENT * 8) return;
    int c = id >> 3, o = (id & 7) * 8;                 // centroid, dim base
    int t = c >> 5, r = c & 31;
    int s = o >> 4, half = (o >> 3) & 1;
    int lane = half * 32 + r;
    const float* src = cb + (size_t)c * W_DIM + o;
    half8 h, l;
#pragma unroll
    for (int j = 0; j < 8; ++j) {
        float w = -2.0f * src[j];
        _Float16 hh = (_Float16)w;                     // RNE
        h[j] = hh;
        l[j] = (_Float16)(w - (float)hh);              // unscaled residual
    }
    size_t base_h = ((size_t)(t * 2 + 0) * 4 + s) * 512 + (size_t)lane * 8;
    size_t base_l = ((size_t)(t * 2 + 1) * 4 + s) * 512 + (size_t)lane * 8;
    *(half8*)(cbf + base_h) = h;
    *(half8*)(cbf + base_l) = l;
}

// ---- pre-kernel 2: c2[c] = ||c||^2 in double (deterministic)
__global__ void c2_kernel(const float* __restrict__ cb, float* __restrict__ c2) {
    int c = blockIdx.x * 256 + threadIdx.x;
    if (c >= K_CENT) return;
    const float4* row = (const float4*)(cb + (size_t)c * W_DIM);
    double s = 0.0;
#pragma unroll
    for (int j = 0; j < W_DIM / 4; ++j) {
        float4 v = row[j];
        s += (double)v.x * v.x + (double)v.y * v.y + (double)v.z * v.z + (double)v.w * v.w;
    }
    c2[c] = (float)s;
}

// Chunk T: 24 MFMAs in FOUR independent chains per wave:
//   am0/am1: hi*hi main chains, 4-deep, C-in = QC (c2, prefetched)
//   ac0/ac1: cross chains (lo_w*hi_x + hi_w*lo_x), 8-deep, C-in = zro
// 8 chains per SIMD-pair -> 256cy issue coverage vs dep-latency L~290.
// Prefetches A(T+1) into NXT* (WAR-free: different buffer) and q(T+1).
#define MFMA_CHUNK(T, CURH, CURL, NXTH, NXTL, QC, QN)                              \
    {                                                                              \
        int t_ = (T);                                                              \
        if (t_ < 15) {                                                             \
            const _Float16* nb = cbf + (size_t)(t_ + 1) * 4096 + (size_t)lane * 8; \
            NXTH[0] = *(const half8*)(nb + 0 * 512);                               \
            NXTH[1] = *(const half8*)(nb + 1 * 512);                               \
            NXTH[2] = *(const half8*)(nb + 2 * 512);                               \
            NXTH[3] = *(const half8*)(nb + 3 * 512);                               \
            NXTL[0] = *(const half8*)(nb + 2048 + 0 * 512);                        \
            NXTL[1] = *(const half8*)(nb + 2048 + 1 * 512);                        \
            NXTL[2] = *(const half8*)(nb + 2048 + 2 * 512);                        \
            NXTL[3] = *(const half8*)(nb + 2048 + 3 * 512);                        \
            QN = *(const f32x16*)&c2s[(t_ + 1) * 32 + half16];                     \
        }                                                                          \
        am0 = __builtin_amdgcn_mfma_f32_32x32x16_f16(CURH[0], b0h[0], QC, 0, 0, 0);  \
        am1 = __builtin_amdgcn_mfma_f32_32x32x16_f16(CURH[0], b1h[0], QC, 0, 0, 0);  \
        ac0 = __builtin_amdgcn_mfma_f32_32x32x16_f16(CURL[0], b0h[0], zro, 0, 0, 0); \
        ac1 = __builtin_amdgcn_mfma_f32_32x32x16_f16(CURL[0], b1h[0], zro, 0, 0, 0); \
        ac0 = __builtin_amdgcn_mfma_f32_32x32x16_f16(CURH[0], b0l[0], ac0, 0, 0, 0); \
        ac1 = __builtin_amdgcn_mfma_f32_32x32x16_f16(CURH[0], b1l[0], ac1, 0, 0, 0); \
        _Pragma("unroll")                                                          \
        for (int s = 1; s < 4; ++s) {                                              \
            am0 = __builtin_amdgcn_mfma_f32_32x32x16_f16(CURH[s], b0h[s], am0, 0, 0, 0); \
            am1 = __builtin_amdgcn_mfma_f32_32x32x16_f16(CURH[s], b1h[s], am1, 0, 0, 0); \
            ac0 = __builtin_amdgcn_mfma_f32_32x32x16_f16(CURL[s], b0h[s], ac0, 0, 0, 0); \
            ac1 = __builtin_amdgcn_mfma_f32_32x32x16_f16(CURL[s], b1h[s], ac1, 0, 0, 0); \
            ac0 = __builtin_amdgcn_mfma_f32_32x32x16_f16(CURH[s], b0l[s], ac0, 0, 0, 0); \
            ac1 = __builtin_amdgcn_mfma_f32_32x32x16_f16(CURH[s], b1l[s], ac1, 0, 0, 0); \
        }                                                                          \
    }

// Binary-descent argmin over 16 values v = AM[j]+AC[j] (c2 already in AM via
// C-in). Ties prefer LEFT -> smallest ji -> first-index-wins (ci monotone in
// ji for fixed half). fmin returns an input bit-exactly so == matches.
#define ARGMIN_TILE(AM, AC, BD, BI, T_)                                        \
    {                                                                          \
        float v0  = AM[0]  + AC[0],  v1  = AM[1]  + AC[1];                     \
        float v2  = AM[2]  + AC[2],  v3  = AM[3]  + AC[3];                     \
        float v4  = AM[4]  + AC[4],  v5  = AM[5]  + AC[5];                     \
        float v6  = AM[6]  + AC[6],  v7  = AM[7]  + AC[7];                     \
        float v8  = AM[8]  + AC[8],  v9  = AM[9]  + AC[9];                     \
        float v10 = AM[10] + AC[10], v11 = AM[11] + AC[11];                    \
        float v12 = AM[12] + AC[12], v13 = AM[13] + AC[13];                    \
        float v14 = AM[14] + AC[14], v15 = AM[15] + AC[15];                    \
        float a0 = fminf(v0, v1),   a1 = fminf(v2, v3);                        \
        float a2 = fminf(v4, v5),   a3 = fminf(v6, v7);                        \
        float a4 = fminf(v8, v9),   a5 = fminf(v10, v11);                      \
        float a6 = fminf(v12, v13), a7 = fminf(v14, v15);                      \
        float b0 = fminf(a0, a1), b1 = fminf(a2, a3);                          \
        float b2 = fminf(a4, a5), b3 = fminf(a6, a7);                          \
        float c0 = fminf(b0, b1), c1 = fminf(b2, b3);                          \
        float m  = fminf(c0, c1);                                              \
        bool  L3 = (m == c0);                                                  \
        float bL = L3 ? b0 : b2;                                               \
        bool  L2 = (m == bL);                                                  \
        float aL = L3 ? (L2 ? a0 : a2) : (L2 ? a4 : a6);                       \
        bool  L1 = (m == aL);                                                  \
        float vE = L3 ? (L2 ? (L1 ? v0 : v2) : (L1 ? v4 : v6))                 \
                      : (L2 ? (L1 ? v8 : v10) : (L1 ? v12 : v14));             \
        bool  L0 = (m == vE);                                                  \
        int ji = (L3 ? 0 : 8) | (L2 ? 0 : 4) | (L1 ? 0 : 2) | (L0 ? 0 : 1);    \
        int ci = (T_) * 32 + half4 + ((ji >> 2) << 3) + (ji & 3);              \
        bool imp = m < BD;                                                     \
        BD = imp ? m : BD;                                                     \
        BI = imp ? ci : BI;                                                    \
    }

#define ARGMIN_CHUNK(T)                                                        \
    {                                                                          \
        ARGMIN_TILE(am0, ac0, bd0, bi0, T)                                     \
        ARGMIN_TILE(am1, ac1, bd1, bi1, T)                                     \
    }

// ---- main kernel: 4 waves/block, each wave TWO 32-point tiles (64 pts).
__global__ __launch_bounds__(256, 2)
void kmeans_mfma(const float* __restrict__ X,
                 const _Float16* __restrict__ cbf,
                 const float* __restrict__ c2,
                 float* __restrict__ out_idx,
                 float* __restrict__ out_dist) {
    // c2 permuted so each lane's 16 C-in values are contiguous:
    // c2s[t*32 + h*16 + j] = c2[t*32 + h*4 + (j>>2)*8 + (j&3)]
    __shared__ __align__(64) float c2s[K_CENT];
    int tid = threadIdx.x;
    {
        int i = tid;
        int t = i >> 5, h = (i >> 4) & 1, j = i & 15;
        c2s[i] = c2[t * 32 + h * 4 + ((j >> 2) << 3) + (j & 3)];
        i = tid + 256;
        t = i >> 5; h = (i >> 4) & 1; j = i & 15;
        c2s[i] = c2[t * 32 + h * 4 + ((j >> 2) << 3) + (j & 3)];
    }
    __syncthreads();

    int wave = tid >> 6;
    int lane = tid & 63;
    int half = lane >> 5;           // 0/1
    int l31  = lane & 31;
    int kb   = half * 8;
    int half4  = half * 4;
    int half16 = half * 16;

    int job = blockIdx.x * 4 + wave;
    if (job >= N_JOBS) return;

    int  p0 = job * 64 + l31;
    bool v1ok = (job * 64 + 32) < N_POINTS;
    int  p1 = v1ok ? (p0 + 32) : p0;

    // ---- load + convert both X tiles (B operands): f16 hi + unscaled lo
    half8 b0h[4], b0l[4], b1h[4], b1l[4];
    float x20 = 0.f, x21 = 0.f;
#pragma unroll
    for (int s = 0; s < 4; ++s) {
        const float4* xa = (const float4*)(X + (size_t)p0 * W_DIM + s * 16 + kb);
        float4 f0 = xa[0], f1 = xa[1];
        float fa[8] = {f0.x, f0.y, f0.z, f0.w, f1.x, f1.y, f1.z, f1.w};
        const float4* xb = (const float4*)(X + (size_t)p1 * W_DIM + s * 16 + kb);
        float4 g0 = xb[0], g1 = xb[1];
        float fb[8] = {g0.x, g0.y, g0.z, g0.w, g1.x, g1.y, g1.z, g1.w};
#pragma unroll
        for (int j = 0; j < 8; ++j) {
            _Float16 h0 = (_Float16)fa[j];
            b0h[s][j] = h0;
            b0l[s][j] = (_Float16)(fa[j] - (float)h0);
            x20 = fmaf(fa[j], fa[j], x20);
            _Float16 h1 = (_Float16)fb[j];
            b1h[s][j] = h1;
            b1l[s][j] = (_Float16)(fb[j] - (float)h1);
            x21 = fmaf(fb[j], fb[j], x21);
        }
    }
    x20 += __shfl_xor(x20, 32);     // halves hold disjoint dims of same point
    x21 += __shfl_xor(x21, 32);

    float bd0 = 3.4e38f, bd1 = 3.4e38f;
    int   bi0 = 0,       bi1 = 0;

    // shared zero C-in for cross chains (read-only)
    f32x16 zro;
#pragma unroll
    for (int j = 0; j < 16; ++j) zro[j] = 0.f;

    // A-fragment double buffers + q double buffers; SINGLE acc set (4 chains)
    half8 ahA[4], alA[4], ahB[4], alB[4];
    f32x16 qP, qQ, am0, am1, ac0, ac1;
    {
        const _Float16* ab = cbf + (size_t)lane * 8;
        ahA[0] = *(const half8*)(ab + 0 * 512);
        ahA[1] = *(const half8*)(ab + 1 * 512);
        ahA[2] = *(const half8*)(ab + 2 * 512);
        ahA[3] = *(const half8*)(ab + 3 * 512);
        alA[0] = *(const half8*)(ab + 2048 + 0 * 512);
        alA[1] = *(const half8*)(ab + 2048 + 1 * 512);
        alA[2] = *(const half8*)(ab + 2048 + 2 * 512);
        alA[3] = *(const half8*)(ab + 2048 + 3 * 512);
    }
    qP = *(const f32x16*)&c2s[0 * 32 + half16];   // q(0)

#pragma unroll 1
    for (int tt = 0; tt < 8; ++tt) {
        MFMA_CHUNK(2 * tt,     ahA, alA, ahB, alB, qP, qQ)
        ARGMIN_CHUNK(2 * tt)
        MFMA_CHUNK(2 * tt + 1, ahB, alB, ahA, alA, qQ, qP)
        ARGMIN_CHUNK(2 * tt + 1)
    }

    // combine the two lane-halves (disjoint centroid rows of the same point)
    {
        float od = __shfl_xor(bd0, 32); int oi = __shfl_xor(bi0, 32);
        if (od < bd0 || (od == bd0 && oi < bi0)) { bd0 = od; bi0 = oi; }
        od = __shfl_xor(bd1, 32); oi = __shfl_xor(bi1, 32);
        if (od < bd1 || (od == bd1 && oi < bi1)) { bd1 = od; bi1 = oi; }
    }

    if (half == 0) {
        out_idx[p0]  = (float)bi0;
        out_dist[p0] = sqrtf(fmaxf(bd0 + x20, 0.f));
        if (v1ok) {
            out_idx[p1]  = (float)bi1;
            out_dist[p1] = sqrtf(fmaxf(bd1 + x21, 0.f));
        }
    }
}

extern "C" void kernel_launch(void* const* d_in, const int* in_sizes, int n_in,
                              void* d_out, int out_size, void* d_ws, size_t ws_size,
                              hipStream_t stream) {
    const float* X  = (const float*)d_in[0];
    const float* cb = (const float*)d_in[1];
    float* out      = (float*)d_out;

    // workspace: fragment-ordered codebook 128KB | c2 2KB
    _Float16* cbf = (_Float16*)d_ws;
    float*    c2  = (float*)(cbf + (size_t)K_CENT * W_DIM * 2);

    hipLaunchKernelGGL(cvt_kernel, dim3((K_CENT * 8 + 255) / 256), dim3(256), 0, stream, cb, cbf);
    hipLaunchKernelGGL(c2_kernel, dim3((K_CENT + 255) / 256), dim3(256), 0, stream, cb, c2);

    hipLaunchKernelGGL(kmeans_mfma, dim3((N_JOBS + 3) / 4), dim3(256), 0, stream,
                       X, cbf, c2, out, out + N_POINTS);
}